// Round 1
// baseline (46.922 us; speedup 1.0000x reference)
//
#include <hip/hip_runtime.h>
#include <math.h>

using f32x4 = __attribute__((ext_vector_type(4))) float;

constexpr float TAU = 0.25f;
constexpr int T  = 16;
constexpr int NPT = 32 * 64 * 32 * 32;   // elements per timestep = 2,097,152
constexpr int HW  = 32 * 32;             // 1024 (divisible by 4 -> a float4 never crosses a channel)
constexpr int C   = 64;
constexpr int NV  = NPT / 4;             // float4 chunks per timestep = 524,288

__global__ __launch_bounds__(256) void lif_fwd(const float* __restrict__ x,
                                               const float* __restrict__ w,
                                               float* __restrict__ out) {
    const int i = blockIdx.x * blockDim.x + threadIdx.x;   // vec4 index in [0, NV)
    const int c = ((i * 4) / HW) % C;                      // channel (same for all 4 lanes of the vec)
    const float thre = (float)tanh((double)w[c]);          // correctly-rounded tanh -> float

    const f32x4* __restrict__ xv = reinterpret_cast<const f32x4*>(x);
    f32x4* __restrict__ ov       = reinterpret_cast<f32x4*>(out);

    f32x4 mem = 0.0f;
    f32x4 spk = 0.0f;

#pragma unroll
    for (int t = 0; t < T; ++t) {
        const f32x4 xt = xv[(size_t)t * NV + i];
        // TAU*mem is exact (x2^-2); (1-spk) is exactly 0 or 1; single rounding at +xt,
        // bit-identical to the numpy reference even under FMA contraction.
        f32x4 u = TAU * mem * (1.0f - spk) + xt;
        f32x4 o;
#pragma unroll
        for (int k = 0; k < 4; ++k) {
            o[k] = (u[k] - thre > 0.0f) ? 1.0f : 0.0f;
        }
        ov[(size_t)t * NV + i] = o;
        mem = u;
        spk = o;
    }
}

extern "C" void kernel_launch(void* const* d_in, const int* in_sizes, int n_in,
                              void* d_out, int out_size, void* d_ws, size_t ws_size,
                              hipStream_t stream) {
    const float* x = (const float*)d_in[0];
    const float* w = (const float*)d_in[1];
    float* out = (float*)d_out;

    dim3 block(256);
    dim3 grid(NV / 256);   // 2048 blocks = 8 per CU
    lif_fwd<<<grid, block, 0, stream>>>(x, w, out);
}